// Round 6
// baseline (3659.393 us; speedup 1.0000x reference)
//
#include <hip/hip_runtime.h>
#include <math.h>

// Problem constants
#define NN     8192      // nodes
#define NEDGE  32768     // edges (before self loops)
#define NETOT  40960     // edges + self loops
#define NG     256       // graphs
#define FXD_   78
#define NH     10        // heads
#define DD2    780       // FXD*HEADS
#define FFD    2048
#define LMUT   735

static inline int cdiv_i(long long a, int b){ return (int)((a + (long long)b - 1) / b); }
static inline int pad32(int x){ return (x + 31) & ~31; }

typedef __attribute__((ext_vector_type(8))) short bf16x8;
typedef __attribute__((ext_vector_type(4))) float f32x4;

static __device__ __forceinline__ unsigned short f2bf(float f){
    unsigned u = __float_as_uint(f);
    u += 0x7FFFu + ((u >> 16) & 1u);
    return (unsigned short)(u >> 16);
}

// async global->LDS, 16B per lane; lds dest is wave-uniform base + lane*16
static __device__ __forceinline__ void gload16(const void* g, void* l){
    __builtin_amdgcn_global_load_lds((const __attribute__((address_space(1))) void*)g,
                                     (__attribute__((address_space(3))) void*)l, 16, 0, 0);
}

// ---------------- fills ----------------
__global__ void fill_f32_k(float* __restrict__ p, float v, long long n){
    long long i = (long long)blockIdx.x * 256 + threadIdx.x;
    if (i < n) p[i] = v;
}
__global__ void fill_u32_k(unsigned* __restrict__ p, unsigned v, long long n){
    long long i = (long long)blockIdx.x * 256 + threadIdx.x;
    if (i < n) p[i] = v;
}

// ---------------- f32 -> bf16 convert with K-padding ----------------
__global__ void cvt_pad_k(const float* __restrict__ src, unsigned short* __restrict__ dst,
                          long long n /*R*ldd*/, int C, int lds_, int ldd)
{
    long long i = (long long)blockIdx.x * 256 + threadIdx.x;
    if (i >= n) return;
    int r = (int)(i / ldd), c = (int)(i % ldd);
    dst[i] = (c < C) ? f2bf(src[(size_t)r * lds_ + c]) : (unsigned short)0;
}

// bf16 transpose: dst[c][r] = src[r][c]
__global__ void tr_bf16_k(const unsigned short* __restrict__ src, unsigned short* __restrict__ dst,
                          int R, int C, int lds_, int ldd)
{
    __shared__ unsigned short t[32][33];
    int cb = blockIdx.x * 32, rb = blockIdx.y * 32;
    int tx = threadIdx.x & 31, ty = threadIdx.x >> 5;   // 32 x 8
#pragma unroll
    for (int i = 0; i < 4; ++i){
        int r = rb + ty + i * 8, c = cb + tx;
        t[ty + i * 8][tx] = (r < R && c < C) ? src[(size_t)r * lds_ + c] : (unsigned short)0;
    }
    __syncthreads();
#pragma unroll
    for (int i = 0; i < 4; ++i){
        int dr = cb + ty + i * 8, dc = rb + tx;
        if (dr < C && dc < R) dst[(size_t)dr * ldd + dc] = t[tx][ty + i * 8];
    }
}

// padded qkv bias: out[s*Ep+c] = (c<E) ? b3[s*E+c] : 0, s=0..2
__global__ void qkv_bias_k(const float* __restrict__ b3, float* __restrict__ out, int E, int Ep)
{
    int idx = blockIdx.x * 256 + threadIdx.x;
    if (idx >= 3 * Ep) return;
    int s = idx / Ep, c = idx % Ep;
    out[idx] = (c < E) ? b3[s * E + c] : 0.f;
}

__global__ void bias_add_k(float* __restrict__ X, const float* __restrict__ b, long long n, int cols)
{
    long long i = (long long)blockIdx.x * 256 + threadIdx.x;
    if (i < n) X[i] += b[i % cols];
}

// ---------------- MFMA bf16 GEMM: 2-phase dbuf + XCD-chunked swizzle ----------------
// C(M,N) = A(M,Kp) x B(N,Kp)^T + bias.  A,B bf16, Kp mult of 32, lda/ldb mult of 8.
// OUTC: 0=f32, 1=bf16.  ACT: 0 none, 1 relu, 2 sigmoid.  BROW: bias indexed by row.
// SPLITK>1: grid.z chunks over K, f32 atomicAdd into pre-zeroed C (no bias/act).
// swz: 0 = x-fast chunking (A-panel locality), 1 = y-fast (B-panel locality).
template<int OUTC, int ACT, int SPLITK, int BROW>
__global__ __launch_bounds__(256) void mgemm_k(
    const unsigned short* __restrict__ A, const unsigned short* __restrict__ B,
    const float* __restrict__ bias, void* __restrict__ Cv,
    int M, int N, int Kp, int lda, int ldb, int ldc, int swz)
{
    __shared__ unsigned short As[2 * 128 * 32];   // double-buffered, linear rows of 32
    __shared__ unsigned short Bs[2 * 128 * 32];
    const int TILE = 128 * 32;
    const int tid = threadIdx.x;
    const int lane = tid & 63, wid = tid >> 6;
    const int r16 = lane & 15, q = lane >> 4;
    const int wr = (wid >> 1) * 64, wc = (wid & 1) * 64;

    // bijective XCD-chunked remap (m204)
    const int gx = gridDim.x, gy = gridDim.y;
    const int nwg = gx * gy;
    int orig = swz ? ((int)blockIdx.x * gy + (int)blockIdx.y)
                   : ((int)blockIdx.y * gx + (int)blockIdx.x);
    int q8 = nwg >> 3, r8 = nwg & 7;
    int xcd = orig & 7, kk8 = orig >> 3;
    int wgid = (xcd < r8 ? xcd * (q8 + 1) : r8 * (q8 + 1) + (xcd - r8) * q8) + kk8;
    int bx, by;
    if (swz){ by = wgid % gy; bx = wgid / gy; }
    else    { bx = wgid % gx; by = wgid / gx; }
    const int row0 = by * 128, col0 = bx * 128;

    int kbeg = 0, kend = Kp;
    if (SPLITK > 1){
        int nt_ = Kp >> 5, cpt = (nt_ + SPLITK - 1) / SPLITK;
        kbeg = (int)blockIdx.z * cpt * 32;
        kend = min(Kp, kbeg + cpt * 32);
    }

    const int c0 = wid * 128 + lane;
    const int r0a = c0 >> 2, k0a = (c0 & 3) << 3;
    const int r1a = r0a + 16, k1a = k0a;
    const size_t gA0 = (size_t)min(row0 + r0a, M - 1) * lda + k0a;
    const size_t gA1 = (size_t)min(row0 + r1a, M - 1) * lda + k1a;
    const size_t gB0 = (size_t)min(col0 + r0a, N - 1) * ldb + k0a;
    const size_t gB1 = (size_t)min(col0 + r1a, N - 1) * ldb + k1a;
    unsigned short* lA = As + wid * 1024;
    unsigned short* lB = Bs + wid * 1024;

    f32x4 acc[4][4];
#pragma unroll
    for (int i = 0; i < 4; ++i)
#pragma unroll
        for (int j = 0; j < 4; ++j){ f32x4 z = {0.f, 0.f, 0.f, 0.f}; acc[i][j] = z; }

    const int nt = (kend - kbeg) >> 5;
    if (nt > 0){
        gload16(A + gA0 + kbeg, lA);
        gload16(A + gA1 + kbeg, lA + 512);
        gload16(B + gB0 + kbeg, lB);
        gload16(B + gB1 + kbeg, lB + 512);
        __syncthreads();
        int cur = 0;
        for (int t = 0; t < nt; ++t){
            const int k0 = kbeg + (t << 5);
            if (t + 1 < nt){
                const int kn = k0 + 32, nb = cur ^ 1;
                gload16(A + gA0 + kn, lA + nb * TILE);
                gload16(A + gA1 + kn, lA + nb * TILE + 512);
                gload16(B + gB0 + kn, lB + nb * TILE);
                gload16(B + gB1 + kn, lB + nb * TILE + 512);
            }
            const unsigned short* Ab = As + cur * TILE;
            const unsigned short* Bb = Bs + cur * TILE;
            bf16x8 af[4], bfv[4];
#pragma unroll
            for (int f = 0; f < 4; ++f){
                af[f]  = *(const bf16x8*)(Ab + (size_t)(wr + f * 16 + r16) * 32 + (q << 3));
                bfv[f] = *(const bf16x8*)(Bb + (size_t)(wc + f * 16 + r16) * 32 + (q << 3));
            }
#pragma unroll
            for (int fi = 0; fi < 4; ++fi)
#pragma unroll
                for (int fj = 0; fj < 4; ++fj)
                    acc[fi][fj] = __builtin_amdgcn_mfma_f32_16x16x32_bf16(af[fi], bfv[fj], acc[fi][fj], 0, 0, 0);
            __syncthreads();
            cur ^= 1;
        }
    }

#pragma unroll
    for (int fi = 0; fi < 4; ++fi){
#pragma unroll
        for (int j = 0; j < 4; ++j){
            int r = row0 + wr + fi * 16 + q * 4 + j;   // C/D: row=(lane>>4)*4+reg
            if (r >= M) continue;
#pragma unroll
            for (int fj = 0; fj < 4; ++fj){
                int c = col0 + wc + fj * 16 + r16;     // C/D: col=lane&15
                if (c >= N) continue;
                float v = acc[fi][fj][j];
                if (SPLITK > 1){
                    atomicAdd((float*)Cv + (size_t)r * ldc + c, v);
                } else {
                    if (bias) v += BROW ? bias[r] : bias[c];
                    if (ACT == 1) v = fmaxf(v, 0.f);
                    if (ACT == 2) v = 1.f / (1.f + expf(-v));
                    if (OUTC == 0) ((float*)Cv)[(size_t)r * ldc + c] = v;
                    else ((unsigned short*)Cv)[(size_t)r * ldc + c] = f2bf(v);
                }
            }
        }
    }
}

template<int OUTC, int ACT, int SPLITK, int BROW>
static void mgemm(hipStream_t s, const unsigned short* A, const unsigned short* B,
                  const float* bias, void* C, int M, int N, int Kp,
                  int lda, int ldb, int ldc, int swz)
{
    dim3 g(cdiv_i(N, 128), cdiv_i(M, 128), SPLITK);
    mgemm_k<OUTC, ACT, SPLITK, BROW><<<g, 256, 0, s>>>(A, B, bias, C, M, N, Kp, lda, ldb, ldc, swz);
}

// ---------------- softmax: 2-pass, register-resident row (8192 cols) ----------------
__global__ __launch_bounds__(256) void softmax_bf16_k(const float* __restrict__ S,
                                                      unsigned short* __restrict__ P, float scale)
{
    __shared__ float red[8];
    const int tid = threadIdx.x;
    const float4* prow = (const float4*)(S + (size_t)blockIdx.x * NN);
    float4 v[8];
    float mx = -3.4e38f;
#pragma unroll
    for (int c = 0; c < 8; ++c){
        float4 t = prow[c * 256 + tid];
        t.x *= scale; t.y *= scale; t.z *= scale; t.w *= scale;
        v[c] = t;
        mx = fmaxf(mx, fmaxf(fmaxf(t.x, t.y), fmaxf(t.z, t.w)));
    }
#pragma unroll
    for (int off = 32; off; off >>= 1) mx = fmaxf(mx, __shfl_xor(mx, off, 64));
    if ((tid & 63) == 0) red[tid >> 6] = mx;
    __syncthreads();
    mx = fmaxf(fmaxf(red[0], red[1]), fmaxf(red[2], red[3]));
    float sum = 0.f;
#pragma unroll
    for (int c = 0; c < 8; ++c){
        v[c].x = expf(v[c].x - mx); v[c].y = expf(v[c].y - mx);
        v[c].z = expf(v[c].z - mx); v[c].w = expf(v[c].w - mx);
        sum += (v[c].x + v[c].y) + (v[c].z + v[c].w);
    }
#pragma unroll
    for (int off = 32; off; off >>= 1) sum += __shfl_xor(sum, off, 64);
    if ((tid & 63) == 0) red[4 + (tid >> 6)] = sum;
    __syncthreads();
    float inv = 1.f / (red[4] + red[5] + red[6] + red[7]);
    ushort4* po = (ushort4*)(P + (size_t)blockIdx.x * NN);
#pragma unroll
    for (int c = 0; c < 8; ++c){
        ushort4 o;
        o.x = f2bf(v[c].x * inv); o.y = f2bf(v[c].y * inv);
        o.z = f2bf(v[c].z * inv); o.w = f2bf(v[c].w * inv);
        po[c * 256 + tid] = o;
    }
}

// ---------------- residual add (+optional Y bias) + layernorm ----------------
__global__ __launch_bounds__(256) void add_ln_k(
    const float* __restrict__ X, const float* __restrict__ Y, const float* __restrict__ ybias,
    const float* __restrict__ g, const float* __restrict__ b,
    float* __restrict__ out, unsigned short* __restrict__ obf, int E, int Ep)
{
    __shared__ float s1[256], s2[256];
    const int tid = threadIdx.x;
    long long base = (long long)blockIdx.x * E;
    float vals[4];
    float sum = 0.f, sq = 0.f;
    int i = 0;
    for (int c = tid; c < Ep; c += 256, ++i){
        float v = 0.f;
        if (c < E){
            v = X[base + c] + Y[base + c];
            if (ybias) v += ybias[c];
            sum += v; sq += v * v;
        }
        vals[i] = v;
    }
    s1[tid] = sum; s2[tid] = sq; __syncthreads();
    for (int s = 128; s; s >>= 1){
        if (tid < s){ s1[tid] += s1[tid + s]; s2[tid] += s2[tid + s]; }
        __syncthreads();
    }
    float mean = s1[0] / (float)E;
    float var = s2[0] / (float)E - mean * mean;
    if (var < 0.f) var = 0.f;
    float inv = 1.f / sqrtf(var + 1e-5f);
    i = 0;
    for (int c = tid; c < Ep; c += 256, ++i){
        if (c < E){
            float o = (vals[i] - mean) * inv * g[c] + b[c];
            out[base + c] = o;
            if (obf) obf[(size_t)blockIdx.x * Ep + c] = f2bf(o);
        } else if (obf) obf[(size_t)blockIdx.x * Ep + c] = 0;
    }
}

// ---------------- GAT ----------------
static __device__ __forceinline__ unsigned enc_f(float x){
    unsigned u = __float_as_uint(x);
    return (u & 0x80000000u) ? ~u : (u | 0x80000000u);
}
static __device__ __forceinline__ float dec_f(unsigned u){
    return (u & 0x80000000u) ? __uint_as_float(u & 0x7fffffffu) : __uint_as_float(~u);
}
static __device__ __forceinline__ void edge_sd(const int* __restrict__ ei, int e, int& s, int& d){
    if (e < NEDGE){ s = ei[e]; d = ei[NEDGE + e]; }
    else { s = e - NEDGE; d = e - NEDGE; }
}

__global__ void gat_srcdst_k(const float* __restrict__ h, const float* __restrict__ aw_src,
                             const float* __restrict__ aw_dst, float* __restrict__ asrc,
                             float* __restrict__ adst)
{
    int idx = blockIdx.x * 256 + threadIdx.x;
    if (idx >= NN * NH) return;
    int n = idx / NH, hh = idx % NH;
    const float* hp = h + (long long)n * DD2 + hh * FXD_;
    const float* ws = aw_src + hh * FXD_;
    const float* wd = aw_dst + hh * FXD_;
    float s1 = 0.f, s2 = 0.f;
    for (int f = 0; f < FXD_; ++f){ float v = hp[f]; s1 += v * ws[f]; s2 += v * wd[f]; }
    asrc[idx] = s1; adst[idx] = s2;
}

__global__ void gat_alpha_k(const int* __restrict__ ei, const float* __restrict__ asrc,
                            const float* __restrict__ adst, float* __restrict__ alpha,
                            unsigned* __restrict__ amax)
{
    int idx = blockIdx.x * 256 + threadIdx.x;
    if (idx >= NETOT * NH) return;
    int e = idx / NH, hh = idx % NH;
    int s, d; edge_sd(ei, e, s, d);
    float a = asrc[s * NH + hh] + adst[d * NH + hh];
    a = (a > 0.f) ? a : 0.2f * a;       // leaky_relu 0.2
    alpha[idx] = a;
    atomicMax(&amax[d * NH + hh], enc_f(a));
}

__global__ void gat_expsum_k(const int* __restrict__ ei, float* __restrict__ alpha,
                             const unsigned* __restrict__ amax, float* __restrict__ denom)
{
    int idx = blockIdx.x * 256 + threadIdx.x;
    if (idx >= NETOT * NH) return;
    int e = idx / NH, hh = idx % NH;
    int s, d; edge_sd(ei, e, s, d);
    float m = dec_f(amax[d * NH + hh]);
    float ex = expf(alpha[idx] - m);
    alpha[idx] = ex;
    atomicAdd(&denom[d * NH + hh], ex);
}

__global__ void deg_count_k(const int* __restrict__ ei, int* __restrict__ deg)
{
    int e = blockIdx.x * 256 + threadIdx.x;
    if (e >= NETOT) return;
    int s, d; edge_sd(ei, e, s, d);
    atomicAdd(&deg[d], 1);
}

__global__ void gat_agg_k(const int* __restrict__ ei, const float* __restrict__ ex,
                          const float* __restrict__ denom, const float* __restrict__ hfeat,
                          float* __restrict__ out)
{
    long long idx = (long long)blockIdx.x * 256 + threadIdx.x;
    if (idx >= (long long)NETOT * DD2) return;
    int e = (int)(idx / DD2), f = (int)(idx % DD2);
    int hh = f / FXD_;
    int s, d; edge_sd(ei, e, s, d);
    float coef = ex[e * NH + hh] / (denom[d * NH + hh] + 1e-16f);
    atomicAdd(&out[(long long)d * DD2 + f], coef * hfeat[(long long)s * DD2 + f]);
}

// bias+relu on f32 (ld=cols), optional padded-bf16 mirror (ld=ldp)
__global__ void bias_relu_k(float* __restrict__ X, const float* __restrict__ b,
                            unsigned short* __restrict__ obf, int rows, int cols, int ldp)
{
    long long i = (long long)blockIdx.x * 256 + threadIdx.x;
    if (i >= (long long)rows * ldp) return;
    int r = (int)(i / ldp), c = (int)(i % ldp);
    if (c < cols){
        float v = X[(size_t)r * cols + c] + b[c];
        v = v > 0.f ? v : 0.f;
        X[(size_t)r * cols + c] = v;
        if (obf) obf[i] = f2bf(v);
    } else if (obf) obf[i] = 0;
}

// ---------------- GCN ----------------
__global__ void dis_k(const int* __restrict__ deg, float* __restrict__ dis)
{
    int n = blockIdx.x * 256 + threadIdx.x;
    if (n >= NN) return;
    float d = (float)deg[n];
    dis[n] = (d > 0.f) ? 1.f / sqrtf(fmaxf(d, 1.f)) : 0.f;
}

__global__ void gcn_agg_k(const int* __restrict__ ei, const float* __restrict__ dis,
                          const float* __restrict__ xw, float* __restrict__ out)
{
    long long idx = (long long)blockIdx.x * 256 + threadIdx.x;
    if (idx >= (long long)NETOT * DD2) return;
    int e = (int)(idx / DD2), f = (int)(idx % DD2);
    int s, d; edge_sd(ei, e, s, d);
    float nrm = dis[s] * dis[d];
    atomicAdd(&out[(long long)d * DD2 + f], nrm * xw[(long long)s * DD2 + f]);
}

// ---------------- graph pooling ----------------
__global__ void pool_accum_k(const float* __restrict__ xg, const int* __restrict__ batch,
                             float* __restrict__ gm, float* __restrict__ ga, int* __restrict__ cnt)
{
    long long idx = (long long)blockIdx.x * 256 + threadIdx.x;
    if (idx >= (long long)NN * DD2) return;
    int n = (int)(idx / DD2), f = (int)(idx % DD2);
    int g = batch[n];
    float v = xg[idx];
    atomicMax((int*)(gm + (long long)g * DD2 + f), __float_as_int(v));
    atomicAdd(ga + (long long)g * DD2 + f, v);
    if (f == 0) atomicAdd(cnt + g, 1);
}

// -> padded bf16 (ld 1568)
__global__ void pool_fin_k(const float* __restrict__ gm, const float* __restrict__ ga,
                           const int* __restrict__ cnt, unsigned short* __restrict__ xdb)
{
    int idx = blockIdx.x * 256 + threadIdx.x;
    if (idx >= NG * 1568) return;
    int g = idx / 1568, c = idx % 1568;
    float v = 0.f;
    if (c < DD2)       v = gm[g * DD2 + c];
    else if (c < 1560) v = ga[g * DD2 + (c - DD2)] / fmaxf((float)cnt[g], 1.f);
    xdb[idx] = f2bf(v);
}

// ---------------- conv autoencoder ----------------
#define BN_SCALE 0.9999950000374996f   // 1/sqrt(1+1e-5)

__global__ void enc1_k(const float* __restrict__ tm, const float* __restrict__ w,
                       const float* __restrict__ bias, const float* __restrict__ bng,
                       const float* __restrict__ bnb, float* __restrict__ out)
{
    int idx = blockIdx.x * 256 + threadIdx.x;       // (NG, 32, 91)
    if (idx >= NG * 32 * 91) return;
    int t = idx % 91, o = (idx / 91) % 32, g = idx / (91 * 32);
    const float* xp = tm + (long long)g * LMUT;
    float mx = -3.4e38f;
    for (int p = 0; p < 8; ++p){
        int base = t * 8 + p;
        float s = bias[o];
        for (int k = 0; k < 8; ++k) s += xp[base + k] * w[o * 8 + k];
        mx = fmaxf(mx, s);
    }
    float v = mx * bng[o] * BN_SCALE + bnb[o];
    out[idx] = v > 0.f ? v : 0.01f * v;
}

__global__ void enc2_k(const float* __restrict__ in, const float* __restrict__ w,
                       const float* __restrict__ bias, const float* __restrict__ bng,
                       const float* __restrict__ bnb, float* __restrict__ out)
{
    int idx = blockIdx.x * 256 + threadIdx.x;       // (NG, 64, 12)
    if (idx >= NG * 64 * 12) return;
    int t = idx % 12, o = (idx / 12) % 64, g = idx / (12 * 64);
    float mx = -3.4e38f;
    for (int p = 0; p < 7; ++p){
        int base = t * 7 + p;
        float s = bias[o];
        for (int i = 0; i < 32; ++i){
            const float* ip = in + ((long long)g * 32 + i) * 91 + base;
            const float* wp = w + (o * 32 + i) * 8;
            for (int k = 0; k < 8; ++k) s += ip[k] * wp[k];
        }
        mx = fmaxf(mx, s);
    }
    float v = mx * bng[o] * BN_SCALE + bnb[o];
    out[idx] = v > 0.f ? v : 0.01f * v;
}

// also emits bf16 flat row (640 per graph) for the z GEMM
__global__ void enc3_k(const float* __restrict__ in, const float* __restrict__ w,
                       const float* __restrict__ bias, float* __restrict__ out,
                       unsigned short* __restrict__ obf)
{
    int idx = blockIdx.x * 256 + threadIdx.x;       // (NG, 128, 5)
    if (idx >= NG * 128 * 5) return;
    int t = idx % 5, o = (idx / 5) % 128, g = idx / (5 * 128);
    float s = bias[o];
    for (int i = 0; i < 64; ++i){
        const float* ip = in + ((long long)g * 64 + i) * 12 + t;
        const float* wp = w + (o * 64 + i) * 8;
        for (int k = 0; k < 8; ++k) s += ip[k] * wp[k];
    }
    out[idx] = s;
    obf[idx] = f2bf(s);
}

__global__ void dec3_k(const float* __restrict__ e3, const float* __restrict__ w,
                       const float* __restrict__ bias, const float* __restrict__ bng,
                       const float* __restrict__ bnb, float* __restrict__ out)
{
    int idx = blockIdx.x * 256 + threadIdx.x;       // (NG, 64, 12)
    if (idx >= NG * 64 * 12) return;
    int t = idx % 12, o = (idx / 12) % 64, g = idx / (12 * 64);
    float s = bias[o];
    for (int i = 0; i < 128; ++i){
        const float* ip = e3 + ((long long)g * 128 + i) * 5;
        const float* wp = w + (i * 64 + o) * 8;
        for (int j = 0; j < 8; ++j){
            int tt = t - j;
            if (tt >= 0 && tt < 5) s += ip[tt] * wp[j];
        }
    }
    float v = s * bng[o] * BN_SCALE + bnb[o];
    out[idx] = v > 0.f ? v : 0.01f * v;
}

__global__ void dec2_k(const float* __restrict__ dd3, const float* __restrict__ w,
                       const float* __restrict__ bias, const float* __restrict__ bng,
                       const float* __restrict__ bnb, float* __restrict__ out)
{
    int idx = blockIdx.x * 256 + threadIdx.x;       // (NG, 32, 91)
    if (idx >= NG * 32 * 91) return;
    int t = idx % 91, o = (idx / 91) % 32, g = idx / (91 * 32);
    float s = bias[o];
    for (int i = 0; i < 64; ++i){
        const float* ip = dd3 + ((long long)g * 64 + i) * 12;
        const float* wp = w + (i * 32 + o) * 8;
        for (int j = 0; j < 8; ++j){
            int tt = t - j;
            if (tt >= 0 && tt < 84) s += ip[tt / 7] * wp[j];   // repeat(7) input
        }
    }
    float v = s * bng[o] * BN_SCALE + bnb[o];
    out[idx] = v > 0.f ? v : 0.01f * v;
}

__global__ void dec1_k(const float* __restrict__ dd2, const float* __restrict__ w,
                       const float* __restrict__ bias, float* __restrict__ out)
{
    int idx = blockIdx.x * 256 + threadIdx.x;       // (NG, 735)
    if (idx >= NG * 735) return;
    int t = idx % 735, g = idx / 735;
    float s = bias[0];
    for (int i = 0; i < 32; ++i){
        const float* ip = dd2 + ((long long)g * 32 + i) * 91;
        const float* wp = w + i * 8;
        for (int j = 0; j < 8; ++j){
            int tt = t - j;
            if (tt >= 0 && tt < 728) s += ip[tt / 8] * wp[j];  // repeat(8) input
        }
    }
    out[idx] = s;
}

__global__ void concat_xc_k(const float* __restrict__ xd, const float* __restrict__ z,
                            unsigned short* __restrict__ xcb)
{
    int idx = blockIdx.x * 256 + threadIdx.x;
    if (idx >= NG * 256) return;
    int g = idx >> 8, c = idx & 255;
    xcb[idx] = f2bf((c < 128) ? xd[g * 128 + c] : z[g * 128 + (c - 128)]);
}

// ---------------- host-side orchestration ----------------
extern "C" void kernel_launch(void* const* d_in, const int* in_sizes, int n_in,
                              void* d_out, int out_size, void* d_ws, size_t ws_size,
                              hipStream_t stream)
{
    (void)in_sizes; (void)n_in; (void)out_size;

    // ---- input pointers: setup_inputs() DICT order (t1 4-15, t2 16-27, gat 28-31) ----
    const float* x      = (const float*)d_in[0];
    const int*   ei     = (const int*)  d_in[1];
    const int*   batch  = (const int*)  d_in[2];
    const float* tmut   = (const float*)d_in[3];
    const float* t1w[12]; for (int i = 0; i < 12; ++i) t1w[i] = (const float*)d_in[4 + i];
    const float* t2w[12]; for (int i = 0; i < 12; ++i) t2w[i] = (const float*)d_in[16 + i];
    const float* gat_w    = (const float*)d_in[28];
    const float* gat_asrc = (const float*)d_in[29];
    const float* gat_adst = (const float*)d_in[30];
    const float* gat_b    = (const float*)d_in[31];
    const float* gcn_w  = (const float*)d_in[32];
    const float* gcn_b  = (const float*)d_in[33];
    const float* fcg1_w = (const float*)d_in[34];
    const float* fcg1_b = (const float*)d_in[35];
    const float* fcg2_w = (const float*)d_in[36];
    const float* fcg2_b = (const float*)d_in[37];
    const float* e1_w = (const float*)d_in[38]; const float* e1_b = (const float*)d_in[39];
    const float* bn1_g = (const float*)d_in[40]; const float* bn1_b = (const float*)d_in[41];
    const float* e2_w = (const float*)d_in[42]; const float* e2_b = (const float*)d_in[43];
    const float* bn2_g = (const float*)d_in[44]; const float* bn2_b = (const float*)d_in[45];
    const float* e3_w = (const float*)d_in[46]; const float* e3_b = (const float*)d_in[47];
    const float* enc_w = (const float*)d_in[48]; const float* enc_b = (const float*)d_in[49];
    const float* d3_w = (const float*)d_in[50]; const float* d3_b = (const float*)d_in[51];
    const float* dbn2_g = (const float*)d_in[52]; const float* dbn2_b = (const float*)d_in[53];
    const float* d2_w = (const float*)d_in[54]; const float* d2_b = (const float*)d_in[55];
    const float* dbn1_g = (const float*)d_in[56]; const float* dbn1_b = (const float*)d_in[57];
    const float* d1_w = (const float*)d_in[58]; const float* d1_b = (const float*)d_in[59];
    const float* fc1_w = (const float*)d_in[60]; const float* fc1_b = (const float*)d_in[61];
    const float* fc2_w = (const float*)d_in[62]; const float* fc2_b = (const float*)d_in[63];
    const float* outw = (const float*)d_in[64]; const float* outb = (const float*)d_in[65];

    // ---- workspace carve (adaptive attention row-block RB) ----
    float *A1, *A2, *A3, *A4, *X1f, *S, *QBIASf;
    unsigned short *XB, *QKVb, *Vt, *HbPb, *Pb;
    unsigned short *WQKVb, *WOUTb, *WL1b, *WL2b, *WGb, *WGCNb, *WFCG1b, *WFCG2b,
                   *WENCb, *WFC1b, *WFC2b, *WOUTWb, *XD16, *FG1b, *E3b, *XCb, *FH1b, *FH2b;
    float *asrc, *adst, *alpha, *denom, *dis, *gm, *ga, *c1p, *c2p, *e3o,
          *zz, *dd3, *dd2b;
    unsigned *amax; int *deg, *cnt;

    auto carve = [&](long long RB) -> size_t {
        char* wp_ = (char*)d_ws;
        auto alc = [&](size_t bytes) -> char* {
            char* p = wp_;
            wp_ += (bytes + 255) & ~(size_t)255;
            return p;
        };
        A1 = (float*)alc((size_t)NN * DD2 * 4);
        A2 = (float*)alc((size_t)NN * DD2 * 4);
        A3 = (float*)alc((size_t)NN * DD2 * 4);
        A4 = (float*)alc((size_t)NN * DD2 * 4);
        X1f = (float*)alc((size_t)NN * FXD_ * 4);
        S   = (float*)alc((size_t)RB * NN * 4);
        XB   = (unsigned short*)alc((size_t)NN * 800 * 2);
        QKVb = (unsigned short*)alc((size_t)NN * 2400 * 2);
        Vt   = (unsigned short*)alc((size_t)800 * NN * 2);
        size_t hb = (size_t)NN * FFD * 2, pb = (size_t)RB * NN * 2;
        HbPb = (unsigned short*)alc(hb > pb ? hb : pb);
        Pb = HbPb;
        WQKVb = (unsigned short*)alc((size_t)2400 * 800 * 2);
        QBIASf= (float*)alc((size_t)2400 * 4);
        WOUTb = (unsigned short*)alc((size_t)780 * 800 * 2);
        WL1b  = (unsigned short*)alc((size_t)2048 * 800 * 2);
        WL2b  = (unsigned short*)alc((size_t)780 * 2048 * 2);
        WGb   = (unsigned short*)alc((size_t)780 * 96 * 2);
        WGCNb = (unsigned short*)alc((size_t)780 * 800 * 2);
        WFCG1b= (unsigned short*)alc((size_t)1500 * 1568 * 2);
        WFCG2b= (unsigned short*)alc((size_t)128 * 1504 * 2);
        WENCb = (unsigned short*)alc((size_t)128 * 640 * 2);
        WFC1b = (unsigned short*)alc((size_t)1024 * 256 * 2);
        WFC2b = (unsigned short*)alc((size_t)128 * 1024 * 2);
        WOUTWb= (unsigned short*)alc((size_t)128 * 2);
        XD16  = (unsigned short*)alc((size_t)NG * 1568 * 2);
        FG1b  = (unsigned short*)alc((size_t)NG * 1504 * 2);
        E3b   = (unsigned short*)alc((size_t)NG * 640 * 2);
        XCb   = (unsigned short*)alc((size_t)NG * 256 * 2);
        FH1b  = (unsigned short*)alc((size_t)NG * 1024 * 2);
        FH2b  = (unsigned short*)alc((size_t)NG * 128 * 2);
        asrc = (float*)alc((size_t)NN * NH * 4);
        adst = (float*)alc((size_t)NN * NH * 4);
        alpha= (float*)alc((size_t)NETOT * NH * 4);
        amax = (unsigned*)alc((size_t)NN * NH * 4);
        denom= (float*)alc((size_t)NN * NH * 4);
        deg  = (int*)alc((size_t)NN * 4);
        dis  = (float*)alc((size_t)NN * 4);
        cnt  = (int*)alc((size_t)NG * 4);
        gm   = (float*)alc((size_t)NG * DD2 * 4);
        ga   = (float*)alc((size_t)NG * DD2 * 4);
        c1p  = (float*)alc((size_t)NG * 32 * 91 * 4);
        c2p  = (float*)alc((size_t)NG * 64 * 12 * 4);
        e3o  = (float*)alc((size_t)NG * 128 * 5 * 4);
        zz   = (float*)alc((size_t)NG * 128 * 4);
        dd3  = (float*)alc((size_t)NG * 64 * 12 * 4);
        dd2b = (float*)alc((size_t)NG * 32 * 91 * 4);
        return (size_t)(wp_ - (char*)d_ws);
    };

    long long RB = 512;
    const long long cands[4] = {8192, 2048, 1024, 512};
    for (int i = 0; i < 4; ++i){ if (carve(cands[i]) <= ws_size){ RB = cands[i]; break; } }
    carve(RB);   // commit chosen layout

    float* out0   = (float*)d_out;                 // (256,1)
    float* xd_out = (float*)d_out + NG;            // (256,128)
    float* decode = (float*)d_out + NG + NG * 128; // (256,735)

    auto cvt = [&](const float* src, unsigned short* dst, int R, int C, int lds_, int ldd){
        long long n = (long long)R * ldd;
        cvt_pad_k<<<cdiv_i(n, 256), 256, 0, stream>>>(src, dst, n, C, lds_, ldd);
    };
    auto zero16 = [&](unsigned short* p, long long nshorts){
        fill_u32_k<<<cdiv_i(nshorts / 2, 256), 256, 0, stream>>>((unsigned*)p, 0u, nshorts / 2);
    };
    auto zerof = [&](float* p, long long n){
        fill_f32_k<<<cdiv_i(n, 256), 256, 0, stream>>>(p, 0.f, n);
    };

    // ---- transformer (shared for t1/t2); xin_bf = XB (padded Ep), residual xin f32 ----
    auto run_tf = [&](const float* xin, const float* const* W, float* outp, int E){
        const int Ep = pad32(E), E3p = 3 * Ep;
        float scale = (float)(1.0 / sqrt((double)E));
        // merged qkv: weights 3*Ep rows (pad rows zero), bias padded
        zero16(WQKVb, (long long)E3p * Ep);
        for (int s = 0; s < 3; ++s)
            cvt(W[0] + (size_t)s * E * E, WQKVb + (size_t)s * Ep * Ep, E, E, E, Ep);
        qkv_bias_k<<<cdiv_i(E3p, 256), 256, 0, stream>>>(W[1], QBIASf, E, Ep);
        mgemm<1,0,1,0>(stream, XB, WQKVb, QBIASf, QKVb, NN, E3p, Ep, Ep, Ep, E3p, 0);
        // V^T via bf16 transpose of the v-part
        {
            dim3 g(cdiv_i(E, 32), cdiv_i(NN, 32));
            tr_bf16_k<<<g, 256, 0, stream>>>(QKVb + 2 * Ep, Vt, NN, E, E3p, NN);
        }
        // attention: S = Q K^T (reads QKVb in place), PV split-K into A4 (f32 atomics)
        zerof(A4, (long long)NN * E);
        for (long long r0 = 0; r0 < NN; r0 += RB){
            mgemm<0,0,1,0>(stream, QKVb + (size_t)r0 * E3p, QKVb + Ep, nullptr, S,
                           (int)RB, NN, Ep, E3p, E3p, NN, 0);
            softmax_bf16_k<<<(int)RB, 256, 0, stream>>>(S, Pb, scale);
            mgemm<0,0,8,0>(stream, Pb, Vt, nullptr, A4 + (size_t)r0 * E,
                           (int)RB, E, NN, NN, NN, E, 0);
        }
        cvt(A4, XB, NN, E, E, Ep);
        // proj (split-K, bias folded into LN) + LN1
        zerof(A2, (long long)NN * E);
        cvt(W[2], WOUTb, E, E, E, Ep);
        mgemm<0,0,4,0>(stream, XB, WOUTb, nullptr, A2, NN, E, Ep, Ep, Ep, E, 0);
        add_ln_k<<<NN, 256, 0, stream>>>(xin, A2, W[3], W[4], W[5], A3, XB, E, Ep);
        // FF1
        cvt(W[6], WL1b, FFD, E, E, Ep);
        mgemm<1,1,1,0>(stream, XB, WL1b, W[7], HbPb, NN, FFD, Ep, Ep, Ep, FFD, 0); // relu, bf16
        // FF2 (split-K, bias folded into LN)
        zerof(A2, (long long)NN * E);
        cvt(W[8], WL2b, E, FFD, FFD, FFD);
        mgemm<0,0,4,0>(stream, HbPb, WL2b, nullptr, A2, NN, E, FFD, FFD, FFD, E, 0);
        add_ln_k<<<NN, 256, 0, stream>>>(A3, A2, W[9], W[10], W[11], outp, XB, E, Ep);
    };

    // ================= t1 transformer (E=78) =================
    cvt(x, XB, NN, FXD_, FXD_, 96);
    run_tf(x, t1w, X1f, FXD_);          // leaves XB = t1 out (ld 96)

    // ================= GAT =================
    cvt(gat_w, WGb, DD2, FXD_, FXD_, 96);
    mgemm<0,0,1,0>(stream, XB, WGb, nullptr, A2, NN, DD2, 96, 96, 96, DD2, 0);   // hfeat
    gat_srcdst_k<<<cdiv_i((long long)NN * NH, 256), 256, 0, stream>>>(A2, gat_asrc, gat_adst, asrc, adst);
    fill_u32_k<<<cdiv_i((long long)NN * NH, 256), 256, 0, stream>>>(amax, 0x007FFFFFu, (long long)NN * NH);
    zerof(denom, (long long)NN * NH);
    fill_u32_k<<<cdiv_i(NN, 256), 256, 0, stream>>>((unsigned*)deg, 0u, NN);
    gat_alpha_k<<<cdiv_i((long long)NETOT * NH, 256), 256, 0, stream>>>(ei, asrc, adst, alpha, amax);
    gat_expsum_k<<<cdiv_i((long long)NETOT * NH, 256), 256, 0, stream>>>(ei, alpha, amax, denom);
    deg_count_k<<<cdiv_i(NETOT, 256), 256, 0, stream>>>(ei, deg);
    zerof(A1, (long long)NN * DD2);
    gat_agg_k<<<cdiv_i((long long)NETOT * DD2, 256), 256, 0, stream>>>(ei, alpha, denom, A2, A1);
    bias_relu_k<<<cdiv_i((long long)NN * 800, 256), 256, 0, stream>>>(A1, gat_b, XB, NN, DD2, 800);

    // ================= t2 transformer (E=780) =================
    run_tf(A1, t2w, A1, DD2);           // leaves XB = t2 out (ld 800)

    // ================= GCN =================
    dis_k<<<cdiv_i(NN, 256), 256, 0, stream>>>(deg, dis);
    zerof(A2, (long long)NN * DD2);
    cvt(gcn_w, WGCNb, DD2, DD2, DD2, 800);
    mgemm<0,0,4,0>(stream, XB, WGCNb, nullptr, A2, NN, DD2, 800, 800, 800, DD2, 0); // xw
    zerof(A3, (long long)NN * DD2);
    gcn_agg_k<<<cdiv_i((long long)NETOT * DD2, 256), 256, 0, stream>>>(ei, dis, A2, A3);
    bias_relu_k<<<cdiv_i((long long)NN * DD2, 256), 256, 0, stream>>>(A3, gcn_b, nullptr, NN, DD2, DD2);

    // ================= pooling + graph head =================
    zerof(gm, (long long)NG * DD2);
    zerof(ga, (long long)NG * DD2);
    fill_u32_k<<<cdiv_i(NG, 256), 256, 0, stream>>>((unsigned*)cnt, 0u, NG);
    pool_accum_k<<<cdiv_i((long long)NN * DD2, 256), 256, 0, stream>>>(A3, batch, gm, ga, cnt);
    pool_fin_k<<<cdiv_i((long long)NG * 1568, 256), 256, 0, stream>>>(gm, ga, cnt, XD16);
    cvt(fcg1_w, WFCG1b, 1500, 1560, 1560, 1568);
    zerof(A2, (long long)NG * 1500);
    mgemm<0,0,8,0>(stream, XD16, WFCG1b, nullptr, A2, NG, 1500, 1568, 1568, 1568, 1500, 0);
    bias_relu_k<<<cdiv_i((long long)NG * 1504, 256), 256, 0, stream>>>(A2, fcg1_b, FG1b, NG, 1500, 1504);
    cvt(fcg2_w, WFCG2b, 128, 1500, 1500, 1504);
    zerof(xd_out, (long long)NG * 128);
    mgemm<0,0,16,0>(stream, FG1b, WFCG2b, nullptr, xd_out, NG, 128, 1504, 1504, 1504, 128, 0);
    bias_add_k<<<cdiv_i((long long)NG * 128, 256), 256, 0, stream>>>(xd_out, fcg2_b, (long long)NG * 128, 128); // OUTPUT 1

    // ================= conv encoder =================
    enc1_k<<<cdiv_i((long long)NG * 32 * 91, 256), 256, 0, stream>>>(tmut, e1_w, e1_b, bn1_g, bn1_b, c1p);
    enc2_k<<<cdiv_i((long long)NG * 64 * 12, 256), 256, 0, stream>>>(c1p, e2_w, e2_b, bn2_g, bn2_b, c2p);
    enc3_k<<<cdiv_i((long long)NG * 128 * 5, 256), 256, 0, stream>>>(c2p, e3_w, e3_b, e3o, E3b);
    cvt(enc_w, WENCb, 128, 640, 640, 640);
    mgemm<0,0,1,0>(stream, E3b, WENCb, enc_b, zz, NG, 128, 640, 640, 640, 128, 0);  // z

    // ================= conv decoder =================
    dec3_k<<<cdiv_i((long long)NG * 64 * 12, 256), 256, 0, stream>>>(e3o, d3_w, d3_b, dbn2_g, dbn2_b, dd3);
    dec2_k<<<cdiv_i((long long)NG * 32 * 91, 256), 256, 0, stream>>>(dd3, d2_w, d2_b, dbn1_g, dbn1_b, dd2b);
    dec1_k<<<cdiv_i((long long)NG * 735, 256), 256, 0, stream>>>(dd2b, d1_w, d1_b, decode); // OUTPUT 2

    // ================= final head =================
    concat_xc_k<<<cdiv_i((long long)NG * 256, 256), 256, 0, stream>>>(xd_out, zz, XCb);
    cvt(fc1_w, WFC1b, 1024, 256, 256, 256);
    mgemm<1,1,1,0>(stream, XCb, WFC1b, fc1_b, FH1b, NG, 1024, 256, 256, 256, 1024, 0);
    cvt(fc2_w, WFC2b, 128, 1024, 1024, 1024);
    zerof(A3, (long long)NG * 128);
    mgemm<0,0,8,0>(stream, FH1b, WFC2b, nullptr, A3, NG, 128, 1024, 1024, 1024, 128, 0);
    bias_relu_k<<<cdiv_i((long long)NG * 128, 256), 256, 0, stream>>>(A3, fc2_b, FH2b, NG, 128, 128);
    cvt(outw, WOUTWb, 1, 128, 128, 128);
    mgemm<0,2,1,0>(stream, FH2b, WOUTWb, outb, out0, NG, 1, 128, 128, 128, 1, 0);   // OUTPUT 0 (sigmoid)
}

// Round 7
// 2354.275 us; speedup vs baseline: 1.5544x; 1.5544x over previous
//
#include <hip/hip_runtime.h>
#include <math.h>

// Problem constants
#define NN     8192      // nodes
#define NEDGE  32768     // edges (before self loops)
#define NETOT  40960     // edges + self loops
#define NG     256       // graphs
#define FXD_   78
#define NH     10        // heads
#define DD2    780       // FXD*HEADS
#define FFD    2048
#define LMUT   735

static inline int cdiv_i(long long a, int b){ return (int)((a + (long long)b - 1) / b); }
static inline int pad32(int x){ return (x + 31) & ~31; }

typedef __attribute__((ext_vector_type(8))) short bf16x8;
typedef __attribute__((ext_vector_type(4))) float f32x4;

static __device__ __forceinline__ unsigned short f2bf(float f){
    unsigned u = __float_as_uint(f);
    u += 0x7FFFu + ((u >> 16) & 1u);
    return (unsigned short)(u >> 16);
}

// async global->LDS, 16B per lane; lds dest is wave-uniform base + lane*16
static __device__ __forceinline__ void gload16(const void* g, void* l){
    __builtin_amdgcn_global_load_lds((const __attribute__((address_space(1))) void*)g,
                                     (__attribute__((address_space(3))) void*)l, 16, 0, 0);
}

// ---------------- fills ----------------
__global__ void fill_f32_k(float* __restrict__ p, float v, long long n){
    long long i = (long long)blockIdx.x * 256 + threadIdx.x;
    if (i < n) p[i] = v;
}
__global__ void fill_u32_k(unsigned* __restrict__ p, unsigned v, long long n){
    long long i = (long long)blockIdx.x * 256 + threadIdx.x;
    if (i < n) p[i] = v;
}

// ---------------- f32 -> bf16 convert with K-padding ----------------
__global__ void cvt_pad_k(const float* __restrict__ src, unsigned short* __restrict__ dst,
                          long long n /*R*ldd*/, int C, int lds_, int ldd)
{
    long long i = (long long)blockIdx.x * 256 + threadIdx.x;
    if (i >= n) return;
    int r = (int)(i / ldd), c = (int)(i % ldd);
    dst[i] = (c < C) ? f2bf(src[(size_t)r * lds_ + c]) : (unsigned short)0;
}

// bf16 transpose: dst[c][r] = src[r][c]
__global__ void tr_bf16_k(const unsigned short* __restrict__ src, unsigned short* __restrict__ dst,
                          int R, int C, int lds_, int ldd)
{
    __shared__ unsigned short t[32][33];
    int cb = blockIdx.x * 32, rb = blockIdx.y * 32;
    int tx = threadIdx.x & 31, ty = threadIdx.x >> 5;   // 32 x 8
#pragma unroll
    for (int i = 0; i < 4; ++i){
        int r = rb + ty + i * 8, c = cb + tx;
        t[ty + i * 8][tx] = (r < R && c < C) ? src[(size_t)r * lds_ + c] : (unsigned short)0;
    }
    __syncthreads();
#pragma unroll
    for (int i = 0; i < 4; ++i){
        int dr = cb + ty + i * 8, dc = rb + tx;
        if (dr < C && dc < R) dst[(size_t)dr * ldd + dc] = t[tx][ty + i * 8];
    }
}

// padded qkv bias: out[s*Ep+c] = (c<E) ? b3[s*E+c] : 0, s=0..2
__global__ void qkv_bias_k(const float* __restrict__ b3, float* __restrict__ out, int E, int Ep)
{
    int idx = blockIdx.x * 256 + threadIdx.x;
    if (idx >= 3 * Ep) return;
    int s = idx / Ep, c = idx % Ep;
    out[idx] = (c < E) ? b3[s * E + c] : 0.f;
}

__global__ void bias_add_k(float* __restrict__ X, const float* __restrict__ b, long long n, int cols)
{
    long long i = (long long)blockIdx.x * 256 + threadIdx.x;
    if (i < n) X[i] += b[i % cols];
}

// ---------------- MFMA bf16 GEMM: 2-phase dbuf + XCD swizzle + BN=64/128 tiles ----------------
// C(M,N) = A(M,Kp) x B(N,Kp)^T + bias.  A,B bf16, Kp mult of 32, lda/ldb mult of 8.
// OUTC: 0=f32, 1=bf16.  ACT: 0 none, 1 relu, 2 sigmoid.  BROW: bias indexed by row.
// SPLITK>1: grid.z chunks over K, f32 atomicAdd into pre-zeroed C (no bias/act).
// BN: output tile cols (128 or 64). BN=64 doubles wg count for skinny-N shapes.
template<int OUTC, int ACT, int SPLITK, int BROW, int BN>
__global__ __launch_bounds__(256) void mgemm_k(
    const unsigned short* __restrict__ A, const unsigned short* __restrict__ B,
    const float* __restrict__ bias, void* __restrict__ Cv,
    int M, int N, int Kp, int lda, int ldb, int ldc, int swz)
{
    constexpr int NFJ   = BN / 32;        // col frags per wave
    constexpr int TILEA = 128 * 32;
    constexpr int TILEB = BN * 32;
    __shared__ unsigned short As[2 * TILEA];
    __shared__ unsigned short Bs[2 * TILEB];
    const int tid = threadIdx.x;
    const int lane = tid & 63, wid = tid >> 6;
    const int r16 = lane & 15, q = lane >> 4;
    const int wr = (wid >> 1) * 64, wc = (wid & 1) * (BN / 2);

    // bijective XCD-chunked remap (m204)
    const int gx = gridDim.x, gy = gridDim.y;
    const int nwg = gx * gy;
    int orig = swz ? ((int)blockIdx.x * gy + (int)blockIdx.y)
                   : ((int)blockIdx.y * gx + (int)blockIdx.x);
    int q8 = nwg >> 3, r8 = nwg & 7;
    int xcd = orig & 7, kk8 = orig >> 3;
    int wgid = (xcd < r8 ? xcd * (q8 + 1) : r8 * (q8 + 1) + (xcd - r8) * q8) + kk8;
    int bx, by;
    if (swz){ by = wgid % gy; bx = wgid / gy; }
    else    { bx = wgid % gx; by = wgid / gx; }
    const int row0 = by * 128, col0 = bx * BN;

    int kbeg = 0, kend = Kp;
    if (SPLITK > 1){
        int nt_ = Kp >> 5, cpt = (nt_ + SPLITK - 1) / SPLITK;
        kbeg = (int)blockIdx.z * cpt * 32;
        kend = min(Kp, kbeg + cpt * 32);
    }

    // A staging: 512 chunks of 16B; lane handles chunk c0 and c0+64
    const int c0 = wid * 128 + lane;
    const int r0a = c0 >> 2, k0a = (c0 & 3) << 3;
    const size_t gA0 = (size_t)min(row0 + r0a, M - 1) * lda + k0a;
    const size_t gA1 = (size_t)min(row0 + r0a + 16, M - 1) * lda + k0a;
    unsigned short* lA = As + wid * 1024;
    // B staging
    size_t gB0 = 0, gB1 = 0;
    unsigned short* lB;
    if (BN == 128){
        gB0 = (size_t)min(col0 + r0a, N - 1) * ldb + k0a;
        gB1 = (size_t)min(col0 + r0a + 16, N - 1) * ldb + k0a;
        lB = Bs + wid * 1024;
    } else {               // BN=64: 256 chunks, 1 per lane
        const int cb = wid * 64 + lane;
        const int rb_ = cb >> 2, kb_ = (cb & 3) << 3;
        gB0 = (size_t)min(col0 + rb_, N - 1) * ldb + kb_;
        lB = Bs + wid * 512;
    }

    f32x4 acc[4][NFJ];
#pragma unroll
    for (int i = 0; i < 4; ++i)
#pragma unroll
        for (int j = 0; j < NFJ; ++j){ f32x4 z = {0.f, 0.f, 0.f, 0.f}; acc[i][j] = z; }

    const int nt = (kend - kbeg) >> 5;
    if (nt > 0){
        gload16(A + gA0 + kbeg, lA);
        gload16(A + gA1 + kbeg, lA + 512);
        gload16(B + gB0 + kbeg, lB);
        if (BN == 128) gload16(B + gB1 + kbeg, lB + 512);
        __syncthreads();
        int cur = 0;
        for (int t = 0; t < nt; ++t){
            const int k0 = kbeg + (t << 5);
            if (t + 1 < nt){                  // stage next tile BEFORE compute (overlap)
                const int kn = k0 + 32, nb = cur ^ 1;
                gload16(A + gA0 + kn, lA + nb * TILEA);
                gload16(A + gA1 + kn, lA + nb * TILEA + 512);
                gload16(B + gB0 + kn, lB + nb * TILEB);
                if (BN == 128) gload16(B + gB1 + kn, lB + nb * TILEB + 512);
            }
            const unsigned short* Ab = As + cur * TILEA;
            const unsigned short* Bb = Bs + cur * TILEB;
            bf16x8 af[4], bfv[NFJ];
#pragma unroll
            for (int f = 0; f < 4; ++f)
                af[f] = *(const bf16x8*)(Ab + (size_t)(wr + f * 16 + r16) * 32 + (q << 3));
#pragma unroll
            for (int f = 0; f < NFJ; ++f)
                bfv[f] = *(const bf16x8*)(Bb + (size_t)(wc + f * 16 + r16) * 32 + (q << 3));
#pragma unroll
            for (int fi = 0; fi < 4; ++fi)
#pragma unroll
                for (int fj = 0; fj < NFJ; ++fj)
                    acc[fi][fj] = __builtin_amdgcn_mfma_f32_16x16x32_bf16(af[fi], bfv[fj], acc[fi][fj], 0, 0, 0);
            __syncthreads();
            cur ^= 1;
        }
    }

#pragma unroll
    for (int fi = 0; fi < 4; ++fi){
#pragma unroll
        for (int j = 0; j < 4; ++j){
            int r = row0 + wr + fi * 16 + q * 4 + j;   // C/D: row=(lane>>4)*4+reg
            if (r >= M) continue;
#pragma unroll
            for (int fj = 0; fj < NFJ; ++fj){
                int c = col0 + wc + fj * 16 + r16;     // C/D: col=lane&15
                if (c >= N) continue;
                float v = acc[fi][fj][j];
                if (SPLITK > 1){
                    atomicAdd((float*)Cv + (size_t)r * ldc + c, v);
                } else {
                    if (bias) v += BROW ? bias[r] : bias[c];
                    if (ACT == 1) v = fmaxf(v, 0.f);
                    if (ACT == 2) v = 1.f / (1.f + expf(-v));
                    if (OUTC == 0) ((float*)Cv)[(size_t)r * ldc + c] = v;
                    else ((unsigned short*)Cv)[(size_t)r * ldc + c] = f2bf(v);
                }
            }
        }
    }
}

template<int OUTC, int ACT, int SPLITK, int BROW, int BN>
static void mgemm(hipStream_t s, const unsigned short* A, const unsigned short* B,
                  const float* bias, void* C, int M, int N, int Kp,
                  int lda, int ldb, int ldc, int swz)
{
    dim3 g(cdiv_i(N, BN), cdiv_i(M, 128), SPLITK);
    mgemm_k<OUTC, ACT, SPLITK, BROW, BN><<<g, 256, 0, s>>>(A, B, bias, C, M, N, Kp, lda, ldb, ldc, swz);
}

// ---------------- softmax: in-place on bf16 rows (8192 cols), register-resident ----------------
__global__ __launch_bounds__(256) void softmax_bf16_k(unsigned short* __restrict__ SP, float scale)
{
    __shared__ float red[8];
    const int tid = threadIdx.x;
    uint4* prow = (uint4*)(SP + (size_t)blockIdx.x * NN);   // 1024 uint4 per row
    float v[32];
    float mx = -3.4e38f;
#pragma unroll
    for (int c = 0; c < 4; ++c){
        uint4 t = prow[c * 256 + tid];
        const unsigned* u = (const unsigned*)&t;
#pragma unroll
        for (int j = 0; j < 4; ++j){
            float lo = __uint_as_float(u[j] << 16) * scale;
            float hi = __uint_as_float(u[j] & 0xFFFF0000u) * scale;
            v[c * 8 + j * 2]     = lo;
            v[c * 8 + j * 2 + 1] = hi;
            mx = fmaxf(mx, fmaxf(lo, hi));
        }
    }
#pragma unroll
    for (int off = 32; off; off >>= 1) mx = fmaxf(mx, __shfl_xor(mx, off, 64));
    if ((tid & 63) == 0) red[tid >> 6] = mx;
    __syncthreads();
    mx = fmaxf(fmaxf(red[0], red[1]), fmaxf(red[2], red[3]));
    float sum = 0.f;
#pragma unroll
    for (int i = 0; i < 32; ++i){ v[i] = expf(v[i] - mx); sum += v[i]; }
#pragma unroll
    for (int off = 32; off; off >>= 1) sum += __shfl_xor(sum, off, 64);
    if ((tid & 63) == 0) red[4 + (tid >> 6)] = sum;
    __syncthreads();
    float inv = 1.f / (red[4] + red[5] + red[6] + red[7]);
#pragma unroll
    for (int c = 0; c < 4; ++c){
        uint4 t;
        unsigned* u = (unsigned*)&t;
#pragma unroll
        for (int j = 0; j < 4; ++j){
            unsigned lo = f2bf(v[c * 8 + j * 2] * inv);
            unsigned hi = f2bf(v[c * 8 + j * 2 + 1] * inv);
            u[j] = lo | (hi << 16);
        }
        prow[c * 256 + tid] = t;
    }
}

// ---------------- residual add (+optional Y bias) + layernorm ----------------
__global__ __launch_bounds__(256) void add_ln_k(
    const float* __restrict__ X, const float* __restrict__ Y, const float* __restrict__ ybias,
    const float* __restrict__ g, const float* __restrict__ b,
    float* __restrict__ out, unsigned short* __restrict__ obf, int E, int Ep)
{
    __shared__ float s1[256], s2[256];
    const int tid = threadIdx.x;
    long long base = (long long)blockIdx.x * E;
    float vals[4];
    float sum = 0.f, sq = 0.f;
    int i = 0;
    for (int c = tid; c < Ep; c += 256, ++i){
        float v = 0.f;
        if (c < E){
            v = X[base + c] + Y[base + c];
            if (ybias) v += ybias[c];
            sum += v; sq += v * v;
        }
        vals[i] = v;
    }
    s1[tid] = sum; s2[tid] = sq; __syncthreads();
    for (int s = 128; s; s >>= 1){
        if (tid < s){ s1[tid] += s1[tid + s]; s2[tid] += s2[tid + s]; }
        __syncthreads();
    }
    float mean = s1[0] / (float)E;
    float var = s2[0] / (float)E - mean * mean;
    if (var < 0.f) var = 0.f;
    float inv = 1.f / sqrtf(var + 1e-5f);
    i = 0;
    for (int c = tid; c < Ep; c += 256, ++i){
        if (c < E){
            float o = (vals[i] - mean) * inv * g[c] + b[c];
            out[base + c] = o;
            if (obf) obf[(size_t)blockIdx.x * Ep + c] = f2bf(o);
        } else if (obf) obf[(size_t)blockIdx.x * Ep + c] = 0;
    }
}

// ---------------- GAT ----------------
static __device__ __forceinline__ unsigned enc_f(float x){
    unsigned u = __float_as_uint(x);
    return (u & 0x80000000u) ? ~u : (u | 0x80000000u);
}
static __device__ __forceinline__ float dec_f(unsigned u){
    return (u & 0x80000000u) ? __uint_as_float(u & 0x7fffffffu) : __uint_as_float(~u);
}
static __device__ __forceinline__ void edge_sd(const int* __restrict__ ei, int e, int& s, int& d){
    if (e < NEDGE){ s = ei[e]; d = ei[NEDGE + e]; }
    else { s = e - NEDGE; d = e - NEDGE; }
}

__global__ void gat_srcdst_k(const float* __restrict__ h, const float* __restrict__ aw_src,
                             const float* __restrict__ aw_dst, float* __restrict__ asrc,
                             float* __restrict__ adst)
{
    int idx = blockIdx.x * 256 + threadIdx.x;
    if (idx >= NN * NH) return;
    int n = idx / NH, hh = idx % NH;
    const float* hp = h + (long long)n * DD2 + hh * FXD_;
    const float* ws = aw_src + hh * FXD_;
    const float* wd = aw_dst + hh * FXD_;
    float s1 = 0.f, s2 = 0.f;
    for (int f = 0; f < FXD_; ++f){ float v = hp[f]; s1 += v * ws[f]; s2 += v * wd[f]; }
    asrc[idx] = s1; adst[idx] = s2;
}

__global__ void gat_alpha_k(const int* __restrict__ ei, const float* __restrict__ asrc,
                            const float* __restrict__ adst, float* __restrict__ alpha,
                            unsigned* __restrict__ amax)
{
    int idx = blockIdx.x * 256 + threadIdx.x;
    if (idx >= NETOT * NH) return;
    int e = idx / NH, hh = idx % NH;
    int s, d; edge_sd(ei, e, s, d);
    float a = asrc[s * NH + hh] + adst[d * NH + hh];
    a = (a > 0.f) ? a : 0.2f * a;       // leaky_relu 0.2
    alpha[idx] = a;
    atomicMax(&amax[d * NH + hh], enc_f(a));
}

__global__ void gat_expsum_k(const int* __restrict__ ei, float* __restrict__ alpha,
                             const unsigned* __restrict__ amax, float* __restrict__ denom)
{
    int idx = blockIdx.x * 256 + threadIdx.x;
    if (idx >= NETOT * NH) return;
    int e = idx / NH, hh = idx % NH;
    int s, d; edge_sd(ei, e, s, d);
    float m = dec_f(amax[d * NH + hh]);
    float ex = expf(alpha[idx] - m);
    alpha[idx] = ex;
    atomicAdd(&denom[d * NH + hh], ex);
}

__global__ void deg_count_k(const int* __restrict__ ei, int* __restrict__ deg)
{
    int e = blockIdx.x * 256 + threadIdx.x;
    if (e >= NETOT) return;
    int s, d; edge_sd(ei, e, s, d);
    atomicAdd(&deg[d], 1);
}

__global__ void gat_agg_k(const int* __restrict__ ei, const float* __restrict__ ex,
                          const float* __restrict__ denom, const float* __restrict__ hfeat,
                          float* __restrict__ out)
{
    long long idx = (long long)blockIdx.x * 256 + threadIdx.x;
    if (idx >= (long long)NETOT * DD2) return;
    int e = (int)(idx / DD2), f = (int)(idx % DD2);
    int hh = f / FXD_;
    int s, d; edge_sd(ei, e, s, d);
    float coef = ex[e * NH + hh] / (denom[d * NH + hh] + 1e-16f);
    atomicAdd(&out[(long long)d * DD2 + f], coef * hfeat[(long long)s * DD2 + f]);
}

// bias+relu on f32 (ld=cols), optional padded-bf16 mirror (ld=ldp)
__global__ void bias_relu_k(float* __restrict__ X, const float* __restrict__ b,
                            unsigned short* __restrict__ obf, int rows, int cols, int ldp)
{
    long long i = (long long)blockIdx.x * 256 + threadIdx.x;
    if (i >= (long long)rows * ldp) return;
    int r = (int)(i / ldp), c = (int)(i % ldp);
    if (c < cols){
        float v = X[(size_t)r * cols + c] + b[c];
        v = v > 0.f ? v : 0.f;
        X[(size_t)r * cols + c] = v;
        if (obf) obf[i] = f2bf(v);
    } else if (obf) obf[i] = 0;
}

// ---------------- GCN ----------------
__global__ void dis_k(const int* __restrict__ deg, float* __restrict__ dis)
{
    int n = blockIdx.x * 256 + threadIdx.x;
    if (n >= NN) return;
    float d = (float)deg[n];
    dis[n] = (d > 0.f) ? 1.f / sqrtf(fmaxf(d, 1.f)) : 0.f;
}

__global__ void gcn_agg_k(const int* __restrict__ ei, const float* __restrict__ dis,
                          const float* __restrict__ xw, float* __restrict__ out)
{
    long long idx = (long long)blockIdx.x * 256 + threadIdx.x;
    if (idx >= (long long)NETOT * DD2) return;
    int e = (int)(idx / DD2), f = (int)(idx % DD2);
    int s, d; edge_sd(ei, e, s, d);
    float nrm = dis[s] * dis[d];
    atomicAdd(&out[(long long)d * DD2 + f], nrm * xw[(long long)s * DD2 + f]);
}

// ---------------- graph pooling ----------------
__global__ void pool_accum_k(const float* __restrict__ xg, const int* __restrict__ batch,
                             float* __restrict__ gm, float* __restrict__ ga, int* __restrict__ cnt)
{
    long long idx = (long long)blockIdx.x * 256 + threadIdx.x;
    if (idx >= (long long)NN * DD2) return;
    int n = (int)(idx / DD2), f = (int)(idx % DD2);
    int g = batch[n];
    float v = xg[idx];
    atomicMax((int*)(gm + (long long)g * DD2 + f), __float_as_int(v));
    atomicAdd(ga + (long long)g * DD2 + f, v);
    if (f == 0) atomicAdd(cnt + g, 1);
}

// -> padded bf16 (ld 1568)
__global__ void pool_fin_k(const float* __restrict__ gm, const float* __restrict__ ga,
                           const int* __restrict__ cnt, unsigned short* __restrict__ xdb)
{
    int idx = blockIdx.x * 256 + threadIdx.x;
    if (idx >= NG * 1568) return;
    int g = idx / 1568, c = idx % 1568;
    float v = 0.f;
    if (c < DD2)       v = gm[g * DD2 + c];
    else if (c < 1560) v = ga[g * DD2 + (c - DD2)] / fmaxf((float)cnt[g], 1.f);
    xdb[idx] = f2bf(v);
}

// ---------------- conv autoencoder ----------------
#define BN_SCALE 0.9999950000374996f   // 1/sqrt(1+1e-5)

__global__ void enc1_k(const float* __restrict__ tm, const float* __restrict__ w,
                       const float* __restrict__ bias, const float* __restrict__ bng,
                       const float* __restrict__ bnb, float* __restrict__ out)
{
    int idx = blockIdx.x * 256 + threadIdx.x;       // (NG, 32, 91)
    if (idx >= NG * 32 * 91) return;
    int t = idx % 91, o = (idx / 91) % 32, g = idx / (91 * 32);
    const float* xp = tm + (long long)g * LMUT;
    float mx = -3.4e38f;
    for (int p = 0; p < 8; ++p){
        int base = t * 8 + p;
        float s = bias[o];
        for (int k = 0; k < 8; ++k) s += xp[base + k] * w[o * 8 + k];
        mx = fmaxf(mx, s);
    }
    float v = mx * bng[o] * BN_SCALE + bnb[o];
    out[idx] = v > 0.f ? v : 0.01f * v;
}

__global__ void enc2_k(const float* __restrict__ in, const float* __restrict__ w,
                       const float* __restrict__ bias, const float* __restrict__ bng,
                       const float* __restrict__ bnb, float* __restrict__ out)
{
    int idx = blockIdx.x * 256 + threadIdx.x;       // (NG, 64, 12)
    if (idx >= NG * 64 * 12) return;
    int t = idx % 12, o = (idx / 12) % 64, g = idx / (12 * 64);
    float mx = -3.4e38f;
    for (int p = 0; p < 7; ++p){
        int base = t * 7 + p;
        float s = bias[o];
        for (int i = 0; i < 32; ++i){
            const float* ip = in + ((long long)g * 32 + i) * 91 + base;
            const float* wp = w + (o * 32 + i) * 8;
            for (int k = 0; k < 8; ++k) s += ip[k] * wp[k];
        }
        mx = fmaxf(mx, s);
    }
    float v = mx * bng[o] * BN_SCALE + bnb[o];
    out[idx] = v > 0.f ? v : 0.01f * v;
}

// also emits bf16 flat row (640 per graph) for the z GEMM
__global__ void enc3_k(const float* __restrict__ in, const float* __restrict__ w,
                       const float* __restrict__ bias, float* __restrict__ out,
                       unsigned short* __restrict__ obf)
{
    int idx = blockIdx.x * 256 + threadIdx.x;       // (NG, 128, 5)
    if (idx >= NG * 128 * 5) return;
    int t = idx % 5, o = (idx / 5) % 128, g = idx / (5 * 128);
    float s = bias[o];
    for (int i = 0; i < 64; ++i){
        const float* ip = in + ((long long)g * 64 + i) * 12 + t;
        const float* wp = w + (o * 64 + i) * 8;
        for (int k = 0; k < 8; ++k) s += ip[k] * wp[k];
    }
    out[idx] = s;
    obf[idx] = f2bf(s);
}

__global__ void dec3_k(const float* __restrict__ e3, const float* __restrict__ w,
                       const float* __restrict__ bias, const float* __restrict__ bng,
                       const float* __restrict__ bnb, float* __restrict__ out)
{
    int idx = blockIdx.x * 256 + threadIdx.x;       // (NG, 64, 12)
    if (idx >= NG * 64 * 12) return;
    int t = idx % 12, o = (idx / 12) % 64, g = idx / (12 * 64);
    float s = bias[o];
    for (int i = 0; i < 128; ++i){
        const float* ip = e3 + ((long long)g * 128 + i) * 5;
        const float* wp = w + (i * 64 + o) * 8;
        for (int j = 0; j < 8; ++j){
            int tt = t - j;
            if (tt >= 0 && tt < 5) s += ip[tt] * wp[j];
        }
    }
    float v = s * bng[o] * BN_SCALE + bnb[o];
    out[idx] = v > 0.f ? v : 0.01f * v;
}

__global__ void dec2_k(const float* __restrict__ dd3, const float* __restrict__ w,
                       const float* __restrict__ bias, const float* __restrict__ bng,
                       const float* __restrict__ bnb, float* __restrict__ out)
{
    int idx = blockIdx.x * 256 + threadIdx.x;       // (NG, 32, 91)
    if (idx >= NG * 32 * 91) return;
    int t = idx % 91, o = (idx / 91) % 32, g = idx / (91 * 32);
    float s = bias[o];
    for (int i = 0; i < 64; ++i){
        const float* ip = dd3 + ((long long)g * 64 + i) * 12;
        const float* wp = w + (i * 32 + o) * 8;
        for (int j = 0; j < 8; ++j){
            int tt = t - j;
            if (tt >= 0 && tt < 84) s += ip[tt / 7] * wp[j];   // repeat(7) input
        }
    }
    float v = s * bng[o] * BN_SCALE + bnb[o];
    out[idx] = v > 0.f ? v : 0.01f * v;
}

__global__ void dec1_k(const float* __restrict__ dd2, const float* __restrict__ w,
                       const float* __restrict__ bias, float* __restrict__ out)
{
    int idx = blockIdx.x * 256 + threadIdx.x;       // (NG, 735)
    if (idx >= NG * 735) return;
    int t = idx % 735, g = idx / 735;
    float s = bias[0];
    for (int i = 0; i < 32; ++i){
        const float* ip = dd2 + ((long long)g * 32 + i) * 91;
        const float* wp = w + i * 8;
        for (int j = 0; j < 8; ++j){
            int tt = t - j;
            if (tt >= 0 && tt < 728) s += ip[tt / 8] * wp[j];  // repeat(8) input
        }
    }
    out[idx] = s;
}

__global__ void concat_xc_k(const float* __restrict__ xd, const float* __restrict__ z,
                            unsigned short* __restrict__ xcb)
{
    int idx = blockIdx.x * 256 + threadIdx.x;
    if (idx >= NG * 256) return;
    int g = idx >> 8, c = idx & 255;
    xcb[idx] = f2bf((c < 128) ? xd[g * 128 + c] : z[g * 128 + (c - 128)]);
}

// ---------------- host-side orchestration ----------------
extern "C" void kernel_launch(void* const* d_in, const int* in_sizes, int n_in,
                              void* d_out, int out_size, void* d_ws, size_t ws_size,
                              hipStream_t stream)
{
    (void)in_sizes; (void)n_in; (void)out_size;

    // ---- input pointers: setup_inputs() DICT order (t1 4-15, t2 16-27, gat 28-31) ----
    const float* x      = (const float*)d_in[0];
    const int*   ei     = (const int*)  d_in[1];
    const int*   batch  = (const int*)  d_in[2];
    const float* tmut   = (const float*)d_in[3];
    const float* t1w[12]; for (int i = 0; i < 12; ++i) t1w[i] = (const float*)d_in[4 + i];
    const float* t2w[12]; for (int i = 0; i < 12; ++i) t2w[i] = (const float*)d_in[16 + i];
    const float* gat_w    = (const float*)d_in[28];
    const float* gat_asrc = (const float*)d_in[29];
    const float* gat_adst = (const float*)d_in[30];
    const float* gat_b    = (const float*)d_in[31];
    const float* gcn_w  = (const float*)d_in[32];
    const float* gcn_b  = (const float*)d_in[33];
    const float* fcg1_w = (const float*)d_in[34];
    const float* fcg1_b = (const float*)d_in[35];
    const float* fcg2_w = (const float*)d_in[36];
    const float* fcg2_b = (const float*)d_in[37];
    const float* e1_w = (const float*)d_in[38]; const float* e1_b = (const float*)d_in[39];
    const float* bn1_g = (const float*)d_in[40]; const float* bn1_b = (const float*)d_in[41];
    const float* e2_w = (const float*)d_in[42]; const float* e2_b = (const float*)d_in[43];
    const float* bn2_g = (const float*)d_in[44]; const float* bn2_b = (const float*)d_in[45];
    const float* e3_w = (const float*)d_in[46]; const float* e3_b = (const float*)d_in[47];
    const float* enc_w = (const float*)d_in[48]; const float* enc_b = (const float*)d_in[49];
    const float* d3_w = (const float*)d_in[50]; const float* d3_b = (const float*)d_in[51];
    const float* dbn2_g = (const float*)d_in[52]; const float* dbn2_b = (const float*)d_in[53];
    const float* d2_w = (const float*)d_in[54]; const float* d2_b = (const float*)d_in[55];
    const float* dbn1_g = (const float*)d_in[56]; const float* dbn1_b = (const float*)d_in[57];
    const float* d1_w = (const float*)d_in[58]; const float* d1_b = (const float*)d_in[59];
    const float* fc1_w = (const float*)d_in[60]; const float* fc1_b = (const float*)d_in[61];
    const float* fc2_w = (const float*)d_in[62]; const float* fc2_b = (const float*)d_in[63];
    const float* outw = (const float*)d_in[64]; const float* outb = (const float*)d_in[65];

    // ---- workspace carve (adaptive attention row-block RB) ----
    float *A1, *A2, *A3, *A4, *X1f, *QBIASf;
    unsigned short *XB, *QKVb, *Vt, *HbPb;
    unsigned short *WQKVb, *WOUTb, *WL1b, *WL2b, *WGb, *WGCNb, *WFCG1b, *WFCG2b,
                   *WENCb, *WFC1b, *WFC2b, *WOUTWb, *XD16, *FG1b, *E3b, *XCb, *FH1b, *FH2b;
    float *asrc, *adst, *alpha, *denom, *dis, *gm, *ga, *c1p, *c2p, *e3o,
          *zz, *dd3, *dd2b;
    unsigned *amax; int *deg, *cnt;

    auto carve = [&](long long RB) -> size_t {
        char* wp_ = (char*)d_ws;
        auto alc = [&](size_t bytes) -> char* {
            char* p = wp_;
            wp_ += (bytes + 255) & ~(size_t)255;
            return p;
        };
        A1 = (float*)alc((size_t)NN * DD2 * 4);
        A2 = (float*)alc((size_t)NN * DD2 * 4);
        A3 = (float*)alc((size_t)NN * DD2 * 4);
        A4 = (float*)alc((size_t)NN * DD2 * 4);
        X1f = (float*)alc((size_t)NN * FXD_ * 4);
        XB   = (unsigned short*)alc((size_t)NN * 800 * 2);
        QKVb = (unsigned short*)alc((size_t)NN * 2400 * 2);
        Vt   = (unsigned short*)alc((size_t)800 * NN * 2);
        size_t hb = (size_t)NN * FFD * 2, pb = (size_t)RB * NN * 2;
        HbPb = (unsigned short*)alc(hb > pb ? hb : pb);   // FF hidden / attention P (bf16)
        WQKVb = (unsigned short*)alc((size_t)2400 * 800 * 2);
        QBIASf= (float*)alc((size_t)2400 * 4);
        WOUTb = (unsigned short*)alc((size_t)780 * 800 * 2);
        WL1b  = (unsigned short*)alc((size_t)2048 * 800 * 2);
        WL2b  = (unsigned short*)alc((size_t)780 * 2048 * 2);
        WGb   = (unsigned short*)alc((size_t)780 * 96 * 2);
        WGCNb = (unsigned short*)alc((size_t)780 * 800 * 2);
        WFCG1b= (unsigned short*)alc((size_t)1500 * 1568 * 2);
        WFCG2b= (unsigned short*)alc((size_t)128 * 1504 * 2);
        WENCb = (unsigned short*)alc((size_t)128 * 640 * 2);
        WFC1b = (unsigned short*)alc((size_t)1024 * 256 * 2);
        WFC2b = (unsigned short*)alc((size_t)128 * 1024 * 2);
        WOUTWb= (unsigned short*)alc((size_t)128 * 2);
        XD16  = (unsigned short*)alc((size_t)NG * 1568 * 2);
        FG1b  = (unsigned short*)alc((size_t)NG * 1504 * 2);
        E3b   = (unsigned short*)alc((size_t)NG * 640 * 2);
        XCb   = (unsigned short*)alc((size_t)NG * 256 * 2);
        FH1b  = (unsigned short*)alc((size_t)NG * 1024 * 2);
        FH2b  = (unsigned short*)alc((size_t)NG * 128 * 2);
        asrc = (float*)alc((size_t)NN * NH * 4);
        adst = (float*)alc((size_t)NN * NH * 4);
        alpha= (float*)alc((size_t)NETOT * NH * 4);
        amax = (unsigned*)alc((size_t)NN * NH * 4);
        denom= (float*)alc((size_t)NN * NH * 4);
        deg  = (int*)alc((size_t)NN * 4);
        dis  = (float*)alc((size_t)NN * 4);
        cnt  = (int*)alc((size_t)NG * 4);
        gm   = (float*)alc((size_t)NG * DD2 * 4);
        ga   = (float*)alc((size_t)NG * DD2 * 4);
        c1p  = (float*)alc((size_t)NG * 32 * 91 * 4);
        c2p  = (float*)alc((size_t)NG * 64 * 12 * 4);
        e3o  = (float*)alc((size_t)NG * 128 * 5 * 4);
        zz   = (float*)alc((size_t)NG * 128 * 4);
        dd3  = (float*)alc((size_t)NG * 64 * 12 * 4);
        dd2b = (float*)alc((size_t)NG * 32 * 91 * 4);
        return (size_t)(wp_ - (char*)d_ws);
    };

    long long RB = 512;
    const long long cands[4] = {8192, 2048, 1024, 512};
    for (int i = 0; i < 4; ++i){ if (carve(cands[i]) <= ws_size){ RB = cands[i]; break; } }
    carve(RB);   // commit chosen layout
    unsigned short* Pb = HbPb;

    float* out0   = (float*)d_out;                 // (256,1)
    float* xd_out = (float*)d_out + NG;            // (256,128)
    float* decode = (float*)d_out + NG + NG * 128; // (256,735)

    auto cvt = [&](const float* src, unsigned short* dst, int R, int C, int lds_, int ldd){
        long long n = (long long)R * ldd;
        cvt_pad_k<<<cdiv_i(n, 256), 256, 0, stream>>>(src, dst, n, C, lds_, ldd);
    };
    auto zero16 = [&](unsigned short* p, long long nshorts){
        fill_u32_k<<<cdiv_i(nshorts / 2, 256), 256, 0, stream>>>((unsigned*)p, 0u, nshorts / 2);
    };
    auto zerof = [&](float* p, long long n){
        fill_f32_k<<<cdiv_i(n, 256), 256, 0, stream>>>(p, 0.f, n);
    };

    // ---- transformer (shared for t1/t2); xin_bf = XB (padded Ep), residual xin f32 ----
    auto run_tf = [&](const float* xin, const float* const* W, float* outp, int E){
        const int Ep = pad32(E), E3p = 3 * Ep;
        float scale = (float)(1.0 / sqrt((double)E));
        // merged qkv: weights 3*Ep rows (pad rows zero), bias padded
        zero16(WQKVb, (long long)E3p * Ep);
        for (int s = 0; s < 3; ++s)
            cvt(W[0] + (size_t)s * E * E, WQKVb + (size_t)s * Ep * Ep, E, E, E, Ep);
        qkv_bias_k<<<cdiv_i(E3p, 256), 256, 0, stream>>>(W[1], QBIASf, E, Ep);
        mgemm<1,0,1,0,128>(stream, XB, WQKVb, QBIASf, QKVb, NN, E3p, Ep, Ep, Ep, E3p, 0);
        // V^T via bf16 transpose of the v-part
        {
            dim3 g(cdiv_i(E, 32), cdiv_i(NN, 32));
            tr_bf16_k<<<g, 256, 0, stream>>>(QKVb + 2 * Ep, Vt, NN, E, E3p, NN);
        }
        // attention: S (bf16, into Pb) -> in-place softmax -> PV
        if (E == FXD_) zerof(A4, (long long)NN * E);   // t1 PV uses split-K atomics
        for (long long r0 = 0; r0 < NN; r0 += RB){
            mgemm<1,0,1,0,128>(stream, QKVb + (size_t)r0 * E3p, QKVb + Ep, nullptr, Pb,
                               (int)RB, NN, Ep, E3p, E3p, NN, 0);
            softmax_bf16_k<<<(int)RB, 256, 0, stream>>>(Pb, scale);
            if (E == FXD_)   // N=78: BN=64 + split-K (atomic out only 2.5MB/slice)
                mgemm<0,0,8,0,64>(stream, Pb, Vt, nullptr, A4 + (size_t)r0 * E,
                                  (int)RB, E, NN, NN, NN, E, 0);
            else             // N=780: BN=64, direct bf16 into XB (pads already 0)
                mgemm<1,0,1,0,64>(stream, Pb, Vt, nullptr, XB + (size_t)r0 * Ep,
                                  (int)RB, E, NN, NN, NN, Ep, 0);
        }
        if (E == FXD_) cvt(A4, XB, NN, E, E, Ep);
        // proj + LN1
        cvt(W[2], WOUTb, E, E, E, Ep);
        mgemm<0,0,1,0,64>(stream, XB, WOUTb, W[3], A2, NN, E, Ep, Ep, Ep, E, 0);
        add_ln_k<<<NN, 256, 0, stream>>>(xin, A2, nullptr, W[4], W[5], A3, XB, E, Ep);
        // FF1 (relu, bf16) -> FF2 -> LN2
        cvt(W[6], WL1b, FFD, E, E, Ep);
        mgemm<1,1,1,0,128>(stream, XB, WL1b, W[7], HbPb, NN, FFD, Ep, Ep, Ep, FFD, 0);
        cvt(W[8], WL2b, E, FFD, FFD, FFD);
        mgemm<0,0,1,0,64>(stream, HbPb, WL2b, W[9], A2, NN, E, FFD, FFD, FFD, E, 0);
        add_ln_k<<<NN, 256, 0, stream>>>(A3, A2, nullptr, W[10], W[11], outp, XB, E, Ep);
    };

    // ================= t1 transformer (E=78) =================
    cvt(x, XB, NN, FXD_, FXD_, 96);
    run_tf(x, t1w, X1f, FXD_);          // leaves XB = t1 out (ld 96)

    // ================= GAT =================
    cvt(gat_w, WGb, DD2, FXD_, FXD_, 96);
    mgemm<0,0,1,0,64>(stream, XB, WGb, nullptr, A2, NN, DD2, 96, 96, 96, DD2, 0);   // hfeat
    gat_srcdst_k<<<cdiv_i((long long)NN * NH, 256), 256, 0, stream>>>(A2, gat_asrc, gat_adst, asrc, adst);
    fill_u32_k<<<cdiv_i((long long)NN * NH, 256), 256, 0, stream>>>(amax, 0x007FFFFFu, (long long)NN * NH);
    zerof(denom, (long long)NN * NH);
    fill_u32_k<<<cdiv_i(NN, 256), 256, 0, stream>>>((unsigned*)deg, 0u, NN);
    gat_alpha_k<<<cdiv_i((long long)NETOT * NH, 256), 256, 0, stream>>>(ei, asrc, adst, alpha, amax);
    gat_expsum_k<<<cdiv_i((long long)NETOT * NH, 256), 256, 0, stream>>>(ei, alpha, amax, denom);
    deg_count_k<<<cdiv_i(NETOT, 256), 256, 0, stream>>>(ei, deg);
    zerof(A1, (long long)NN * DD2);
    gat_agg_k<<<cdiv_i((long long)NETOT * DD2, 256), 256, 0, stream>>>(ei, alpha, denom, A2, A1);
    bias_relu_k<<<cdiv_i((long long)NN * 800, 256), 256, 0, stream>>>(A1, gat_b, XB, NN, DD2, 800);

    // ================= t2 transformer (E=780) =================
    run_tf(A1, t2w, A1, DD2);           // leaves XB = t2 out (ld 800)

    // ================= GCN =================
    dis_k<<<cdiv_i(NN, 256), 256, 0, stream>>>(deg, dis);
    cvt(gcn_w, WGCNb, DD2, DD2, DD2, 800);
    mgemm<0,0,1,0,64>(stream, XB, WGCNb, nullptr, A2, NN, DD2, 800, 800, 800, DD2, 0); // xw
    zerof(A3, (long long)NN * DD2);
    gcn_agg_k<<<cdiv_i((long long)NETOT * DD2, 256), 256, 0, stream>>>(ei, dis, A2, A3);
    bias_relu_k<<<cdiv_i((long long)NN * DD2, 256), 256, 0, stream>>>(A3, gcn_b, nullptr, NN, DD2, DD2);

    // ================= pooling + graph head =================
    zerof(gm, (long long)NG * DD2);
    zerof(ga, (long long)NG * DD2);
    fill_u32_k<<<cdiv_i(NG, 256), 256, 0, stream>>>((unsigned*)cnt, 0u, NG);
    pool_accum_k<<<cdiv_i((long long)NN * DD2, 256), 256, 0, stream>>>(A3, batch, gm, ga, cnt);
    pool_fin_k<<<cdiv_i((long long)NG * 1568, 256), 256, 0, stream>>>(gm, ga, cnt, XD16);
    cvt(fcg1_w, WFCG1b, 1500, 1560, 1560, 1568);
    zerof(A2, (long long)NG * 1500);
    mgemm<0,0,8,0,64>(stream, XD16, WFCG1b, nullptr, A2, NG, 1500, 1568, 1568, 1568, 1500, 0);
    bias_relu_k<<<cdiv_i((long long)NG * 1504, 256), 256, 0, stream>>>(A2, fcg1_b, FG1b, NG, 1500, 1504);
    cvt(fcg2_w, WFCG2b, 128, 1500, 1500, 1504);
    zerof(xd_out, (long long)NG * 128);
    mgemm<0,0,16,0,128>(stream, FG1b, WFCG2b, nullptr, xd_out, NG, 128, 1504, 1504, 1504, 128, 0);
    bias_add_k<<<cdiv_i((long long)NG * 128, 256), 256, 0, stream>>>(xd_out, fcg2_b, (long long)NG * 128, 128); // OUTPUT 1

    // ================= conv encoder =================
    enc1_k<<<cdiv_i((long long)NG * 32 * 91, 256), 256, 0, stream>>>(tmut, e1_w, e1_b, bn1_g, bn1_b, c1p);
    enc2_k<<<cdiv_i((long long)NG * 64 * 12, 256), 256, 0, stream>>>(c1p, e2_w, e2_b, bn2_g, bn2_b, c2p);
    enc3_k<<<cdiv_i((long long)NG * 128 * 5, 256), 256, 0, stream>>>(c2p, e3_w, e3_b, e3o, E3b);
    cvt(enc_w, WENCb, 128, 640, 640, 640);
    mgemm<0,0,1,0,128>(stream, E3b, WENCb, enc_b, zz, NG, 128, 640, 640, 640, 128, 0);  // z

    // ================= conv decoder =================
    dec3_k<<<cdiv_i((long long)NG * 64 * 12, 256), 256, 0, stream>>>(e3o, d3_w, d3_b, dbn2_g, dbn2_b, dd3);
    dec2_k<<<cdiv_i((long long)NG * 32 * 91, 256), 256, 0, stream>>>(dd3, d2_w, d2_b, dbn1_g, dbn1_b, dd2b);
    dec1_k<<<cdiv_i((long long)NG * 735, 256), 256, 0, stream>>>(dd2b, d1_w, d1_b, decode); // OUTPUT 2

    // ================= final head =================
    concat_xc_k<<<cdiv_i((long long)NG * 256, 256), 256, 0, stream>>>(xd_out, zz, XCb);
    cvt(fc1_w, WFC1b, 1024, 256, 256, 256);
    mgemm<1,1,1,0,128>(stream, XCb, WFC1b, fc1_b, FH1b, NG, 1024, 256, 256, 256, 1024, 0);
    cvt(fc2_w, WFC2b, 128, 1024, 1024, 1024);
    zerof(A3, (long long)NG * 128);
    mgemm<0,0,8,0,128>(stream, FH1b, WFC2b, nullptr, A3, NG, 128, 1024, 1024, 1024, 128, 0);
    bias_relu_k<<<cdiv_i((long long)NG * 128, 256), 256, 0, stream>>>(A3, fc2_b, FH2b, NG, 128, 128);
    cvt(outw, WOUTWb, 1, 128, 128, 128);
    mgemm<0,2,1,0,64>(stream, FH2b, WOUTWb, outb, out0, NG, 1, 128, 128, 128, 1, 0);   // OUTPUT 0 (sigmoid)
}